// Round 4
// baseline (1142.257 us; speedup 1.0000x reference)
//
#include <hip/hip_runtime.h>

#define ENC_NEGINF 0x007FFFFFu
#define NN_FINE 100000
#define NN_COARSE 1800
#define INV_N  (1.0f / 100000.0f)
#define INV_N2 (1.0f / 1800.0f)

__device__ __forceinline__ unsigned enc_f(float f) {
    unsigned u = __float_as_uint(f);
    return (u & 0x80000000u) ? ~u : (u | 0x80000000u);
}
__device__ __forceinline__ float dec_f(unsigned k) {
    return (k & 0x80000000u) ? __uint_as_float(k & 0x7fffffffu) : __uint_as_float(~k);
}

// bijective XCD-aware swizzle (m204 variant)
__device__ __forceinline__ int xcd_swz(int bid, int nwg) {
    int q = nwg >> 3, r = nwg & 7;
    int xcd = bid & 7, idx = bid >> 3;
    return (xcd < r ? xcd * (q + 1) : r * (q + 1) + (xcd - r) * q) + idx;
}

__device__ __forceinline__ float2 bn_ss(const float* __restrict__ st,
                                        const float* __restrict__ g,
                                        const float* __restrict__ be,
                                        int r, float invn) {
    float mu  = st[r] * invn;
    float var = fmaxf(st[128 + r] * invn - mu * mu, 0.f);
    float s = g[r] * rsqrtf(var + 1e-5f);
    return make_float2(s, be[r] - mu * s);
}

// ---------------- init: zero BN stats --------------------------------------
__global__ void init_k(float* stats) {
    int t = blockIdx.x * blockDim.x + threadIdx.x;
    if (t < 1280) stats[t] = 0.f;
}

// ---------------- PassA: per (node, channel-pair) ---------------------------
// MODE 0: f=in. 1: f=bn(in), write zout=bn(in). 2: f=bn(in)+skipf.
template<int CIN, int COUT, int MODE>
__global__ void pass_a(const float* __restrict__ in,
                       const float* __restrict__ st, const float* __restrict__ g,
                       const float* __restrict__ be, float invn,
                       const float* __restrict__ skipf,
                       const float* __restrict__ wl, const float* __restrict__ wsrc,
                       const float* __restrict__ wpos, const float* __restrict__ bpos,
                       const float* __restrict__ pos,
                       float4* __restrict__ SHP, float2* __restrict__ CAP,
                       float* __restrict__ zout, int NN) {
    constexpr int P = COUT / 2;
    int idx = blockIdx.x * blockDim.x + threadIdx.x;
    int i = idx / P, p = idx % P;
    if (i >= NN) return;
    float f[CIN];
#pragma unroll
    for (int r = 0; r < CIN; ++r) {
        float v = in[i * CIN + r];
        if constexpr (MODE >= 1) {
            float2 ss = bn_ss(st, g, be, r, invn);
            v = v * ss.x + ss.y;
        }
        if constexpr (MODE == 2) v += skipf[i * CIN + r];
        f[r] = v;
    }
    int c0 = 2 * p;
    float h0 = 0.f, a0 = 0.f, h1 = 0.f, a1 = 0.f;
#pragma unroll
    for (int r = 0; r < CIN; ++r) {
        float2 wlr = *reinterpret_cast<const float2*>(&wl[r * COUT + c0]);
        float2 wsr = *reinterpret_cast<const float2*>(&wsrc[r * COUT + c0]);
        h0 += f[r] * wlr.x; h1 += f[r] * wlr.y;
        a0 += f[r] * wsr.x; a1 += f[r] * wsr.y;
    }
    float px = pos[i * 3], py = pos[i * 3 + 1], pz = pos[i * 3 + 2];
    float2 w0 = *reinterpret_cast<const float2*>(&wpos[c0]);
    float2 w1 = *reinterpret_cast<const float2*>(&wpos[COUT + c0]);
    float2 w2 = *reinterpret_cast<const float2*>(&wpos[2 * COUT + c0]);
    float pd0 = px * w0.x + py * w1.x + pz * w2.x;
    float pd1 = px * w0.y + py * w1.y + pz * w2.y;
    float2 bp = *reinterpret_cast<const float2*>(&bpos[c0]);
    SHP[i * P + p] = make_float4(a0 + pd0, a1 + pd1, h0 - pd0, h1 - pd1);
    CAP[i * P + p] = make_float2(pd0 + bp.x, pd1 + bp.y);
    if constexpr (MODE == 1) {
        float2 s0 = bn_ss(st, g, be, c0, invn);
        float2 s1 = bn_ss(st, g, be, c0 + 1, invn);
        float2 zv = make_float2(in[i * CIN + c0] * s0.x + s0.y,
                                in[i * CIN + c0 + 1] * s1.x + s1.y);
        *reinterpret_cast<float2*>(&zout[i * CIN + c0]) = zv;
    }
}

// ---------------- Edge pass: 1 float4 gather per edge, no atomics -----------
template<int C, bool COARSE>
__global__ __launch_bounds__(256, 4)
void edge_pass(const float4* __restrict__ SHP, const float2* __restrict__ CAP,
               const int* __restrict__ esrc, float2* __restrict__ y2, int NN) {
    constexpr int P = C / 2;
    constexpr int NPB = 256 / P;
    constexpr int DEG_ = COARSE ? 8 : 16;
    __shared__ int se[NPB * DEG_];
    int bid = COARSE ? (int)blockIdx.x : xcd_swz(blockIdx.x, gridDim.x);
    int tid = threadIdx.x;
    int node0 = bid * NPB;
    if constexpr (!COARSE) {
        for (int t = tid; t < NPB * DEG_; t += 256)
            se[t] = esrc[node0 * 16 + t];          // in-bounds: dst half follows src
    } else {
        for (int t = tid; t < NPB * DEG_; t += 256) {
            int n = t / DEG_, e = t % DEG_;
            int i2 = node0 + n;
            if (i2 < NN) {
                int b = i2 / 225, j = i2 % 225;
                se[t] = esrc[b * 1800 + e * 225 + j];
            }
        }
    }
    __syncthreads();
    int n = tid / P, p = tid % P;
    int i = node0 + n;
    if (i >= NN) return;

    float4 q[DEG_ + 1];
#pragma unroll
    for (int e = 0; e < DEG_; ++e)
        q[e] = SHP[(size_t)se[n * DEG_ + e] * P + p];
    q[DEG_] = SHP[(size_t)i * P + p];

    float smin0 = q[0].x, smin1 = q[0].y;
#pragma unroll
    for (int e = 1; e <= DEG_; ++e) {
        smin0 = fminf(smin0, q[e].x);
        smin1 = fminf(smin1, q[e].y);
    }
    float den0 = 0.f, acc0 = 0.f, den1 = 0.f, acc1 = 0.f;
#pragma unroll
    for (int e = 0; e <= DEG_; ++e) {
        float ex0 = __expf(smin0 - q[e].x);
        float ex1 = __expf(smin1 - q[e].y);
        den0 += ex0; acc0 += ex0 * q[e].z;
        den1 += ex1; acc1 += ex1 * q[e].w;
    }
    float2 Ci = CAP[(size_t)i * P + p];
    float o0 = (acc0 + Ci.x * den0) / (den0 + 1e-16f);
    float o1 = (acc1 + Ci.y * den1) / (den1 + 1e-16f);
    float y0 = o0 > 0.f ? o0 : (__expf(o0) - 1.f);
    float y1 = o1 > 0.f ? o1 : (__expf(o1) - 1.f);
    y2[(size_t)i * P + p] = make_float2(y0, y1);
}

// ---------------- BN stats over y -------------------------------------------
template<int C>
__global__ void stats_k(const float* __restrict__ y, int total,
                        float* __restrict__ stats) {
    __shared__ float ls[C], lq[C];
    int tid = threadIdx.x;
    if (tid < C) { ls[tid] = 0.f; lq[tid] = 0.f; }
    __syncthreads();
    float s1 = 0.f, s2 = 0.f;
    int stride = gridDim.x * 256;
    int c = tid % C;   // stride and block offset are multiples of C
    for (int k = blockIdx.x * 256 + tid; k < total; k += stride) {
        float v = y[k];
        s1 += v; s2 += v * v;
    }
    if constexpr (C <= 32) {
#pragma unroll
        for (int m = C; m < 64; m <<= 1) {
            s1 += __shfl_xor(s1, m);
            s2 += __shfl_xor(s2, m);
        }
        if ((tid & 63) < C) { atomicAdd(&ls[c], s1); atomicAdd(&lq[c], s2); }
    } else {
        atomicAdd(&ls[c], s1); atomicAdd(&lq[c], s2);
    }
    __syncthreads();
    if (tid < C) {
        atomicAdd(&stats[tid], ls[tid]);
        atomicAdd(&stats[128 + tid], lq[tid]);
    }
}

// ---------------- pool3: one block per sample, LDS max/mean, direct store ---
__global__ __launch_bounds__(256)
void pool3_k(const float* __restrict__ y3, const float* __restrict__ st,
             const float* __restrict__ g, const float* __restrict__ be,
             const float* __restrict__ pos,
             float* __restrict__ X2, float* __restrict__ POS2) {
    __shared__ unsigned lkey[7200];   // 225 clusters x 32 ch
    __shared__ float lcnt[225];
    __shared__ float lpac[675];
    int tid = threadIdx.x;
    for (int t = tid; t < 7200; t += 256) lkey[t] = ENC_NEGINF;
    if (tid < 225) lcnt[tid] = 0.f;
    for (int t = tid; t < 675; t += 256) lpac[t] = 0.f;
    __syncthreads();
    int s = blockIdx.x;
    int c = tid & 31, nl = tid >> 5;
    float2 ss = bn_ss(st, g, be, c, INV_N);
    int nbeg = s * 12500, nend = nbeg + 12500;
    for (int i = nbeg + nl; i < nend; i += 8) {
        float z = y3[(size_t)i * 32 + c] * ss.x + ss.y;
        float px = pos[i * 3], py = pos[i * 3 + 1];
        int cx = min(max((int)floorf(px / 16.f), 0), 14);
        int cy = min(max((int)floorf(py / 12.f), 0), 14);
        int cl = cy * 15 + cx;
        atomicMax(&lkey[cl * 32 + c], enc_f(z));
        if (c == 0) {
            atomicAdd(&lcnt[cl], 1.f);
            atomicAdd(&lpac[cl * 3 + 0], px);
            atomicAdd(&lpac[cl * 3 + 1], py);
            atomicAdd(&lpac[cl * 3 + 2], pos[i * 3 + 2]);
        }
    }
    __syncthreads();
    for (int t = tid; t < 7200; t += 256) {
        unsigned k = lkey[t];
        X2[s * 7200 + t] = (k == ENC_NEGINF) ? 0.f : dec_f(k);
    }
    for (int t = tid; t < 675; t += 256)
        POS2[s * 675 + t] = lpac[t] / fmaxf(lcnt[t / 3], 1.f);
}

// ---------------- pool5: one block per sample, LDS max, direct store --------
__global__ __launch_bounds__(256)
void pool5_k(const float* __restrict__ y5, const float* __restrict__ st,
             const float* __restrict__ g, const float* __restrict__ be,
             const float* __restrict__ POS2, float* __restrict__ POOLED) {
    __shared__ unsigned lkey[2048];   // 16 cells x 128 ch
    int tid = threadIdx.x;
    for (int t = tid; t < 2048; t += 256) lkey[t] = ENC_NEGINF;
    __syncthreads();
    int s = blockIdx.x;
    int c = tid & 127, nl = tid >> 7;
    float2 ss = bn_ss(st, g, be, c, INV_N2);
    for (int j = nl; j < 225; j += 2) {
        int i = s * 225 + j;
        float z = y5[(size_t)i * 128 + c] * ss.x + ss.y;
        float px = POS2[i * 3], py = POS2[i * 3 + 1];
        int cx = min(max((int)floorf(px / 60.f), 0), 3);
        int cy = min(max((int)floorf(py / 45.f), 0), 3);
        int cell = (cy * 4 + cx) * 128 + c;
        atomicMax(&lkey[cell], enc_f(z));
    }
    __syncthreads();
    for (int t = tid; t < 2048; t += 256) {
        unsigned k = lkey[t];
        POOLED[s * 2048 + t] = (k == ENC_NEGINF) ? 0.f : dec_f(k);
    }
}

// ---------------- FC --------------------------------------------------------
__global__ void fc_k(const float* __restrict__ pooled, const float* __restrict__ wfc,
                     float* __restrict__ out) {
    __shared__ float row[2048];
    int b = blockIdx.x;
    for (int k = threadIdx.x; k < 2048; k += 256)
        row[k] = pooled[b * 2048 + k];
    __syncthreads();
    int wave = threadIdx.x >> 6, lane = threadIdx.x & 63;
    int o = blockIdx.y * 4 + wave;
    if (o < 101) {
        float a = 0.f;
        for (int k = lane; k < 2048; k += 64)
            a += row[k] * wfc[k * 101 + o];
#pragma unroll
        for (int m = 32; m; m >>= 1) a += __shfl_xor(a, m);
        if (lane == 0) out[b * 101 + o] = a;
    }
}

extern "C" void kernel_launch(void* const* d_in, const int* in_sizes, int n_in,
                              void* d_out, int out_size, void* d_ws, size_t ws_size,
                              hipStream_t stream) {
    const float* x     = (const float*)d_in[0];
    const float* pos   = (const float*)d_in[1];
    const int*   e1    = (const int*)d_in[3];
    const int*   e2    = (const int*)d_in[4];
    const float* w_fc  = (const float*)d_in[40];
    auto WL = [&](int l) { return (const float*)d_in[5 + l * 7 + 0]; };
    auto WS = [&](int l) { return (const float*)d_in[5 + l * 7 + 1]; };
    auto WP = [&](int l) { return (const float*)d_in[5 + l * 7 + 3]; };
    auto BP = [&](int l) { return (const float*)d_in[5 + l * 7 + 4]; };
    auto G_ = [&](int l) { return (const float*)d_in[5 + l * 7 + 5]; };
    auto BE = [&](int l) { return (const float*)d_in[5 + l * 7 + 6]; };

    float* W = (float*)d_ws;
    size_t o = 0;
    float4* SHPf = (float4*)W;        o += 6400000;  // N*16 float4 (L1..L3)
    float2* CAPf = (float2*)(W + o);  o += 3200000;
    float*  Y1   = W + o;             o += 800000;
    float*  Y2   = W + o;             o += 800000;
    float*  Z1   = W + o;             o += 800000;
    float*  Y3   = W + o;             o += 3200000;
    float*  STATS = W + o;            o += 5 * 256;
    float*  X2   = W + o;             o += 57600;
    float*  POS2 = W + o;             o += 5400;
    float4* SHPc = (float4*)(W + o);  o += 460800;   // 1800*64 float4
    float2* CAPc = (float2*)(W + o);  o += 230400;
    float*  Y4   = W + o;             o += 57600;
    float*  Y5   = W + o;             o += 230400;
    float*  POOLED = W + o;           o += 16384;

    hipLaunchKernelGGL(init_k, dim3(5), dim3(256), 0, stream, STATS);

    // ---- L1 (1->8) fine ----
    hipLaunchKernelGGL((pass_a<1, 8, 0>), dim3(1563), dim3(256), 0, stream,
                       x, nullptr, nullptr, nullptr, 0.f, nullptr,
                       WL(0), WS(0), WP(0), BP(0), pos,
                       SHPf, CAPf, nullptr, NN_FINE);
    hipLaunchKernelGGL((edge_pass<8, false>), dim3(1563), dim3(256), 0, stream,
                       SHPf, CAPf, e1, (float2*)Y1, NN_FINE);
    hipLaunchKernelGGL((stats_k<8>), dim3(64), dim3(256), 0, stream,
                       Y1, 800000, STATS + 0);

    // ---- L2 (8->8) fine, writes Z1=bn(Y1) ----
    hipLaunchKernelGGL((pass_a<8, 8, 1>), dim3(1563), dim3(256), 0, stream,
                       Y1, STATS + 0, G_(0), BE(0), INV_N, nullptr,
                       WL(1), WS(1), WP(1), BP(1), pos,
                       SHPf, CAPf, Z1, NN_FINE);
    hipLaunchKernelGGL((edge_pass<8, false>), dim3(1563), dim3(256), 0, stream,
                       SHPf, CAPf, e1, (float2*)Y2, NN_FINE);
    hipLaunchKernelGGL((stats_k<8>), dim3(64), dim3(256), 0, stream,
                       Y2, 800000, STATS + 256);

    // ---- L3 (8->32) fine, f = bn(Y2)+Z1 ----
    hipLaunchKernelGGL((pass_a<8, 32, 2>), dim3(6250), dim3(256), 0, stream,
                       Y2, STATS + 256, G_(1), BE(1), INV_N, Z1,
                       WL(2), WS(2), WP(2), BP(2), pos,
                       SHPf, CAPf, nullptr, NN_FINE);
    hipLaunchKernelGGL((edge_pass<32, false>), dim3(6250), dim3(256), 0, stream,
                       SHPf, CAPf, e1, (float2*)Y3, NN_FINE);
    hipLaunchKernelGGL((stats_k<32>), dim3(64), dim3(256), 0, stream,
                       Y3, 3200000, STATS + 512);

    // ---- pool3: one block per sample ----
    hipLaunchKernelGGL(pool3_k, dim3(8), dim3(256), 0, stream,
                       Y3, STATS + 512, G_(2), BE(2), pos, X2, POS2);

    // ---- L4 (32->32) coarse ----
    hipLaunchKernelGGL((pass_a<32, 32, 0>), dim3(113), dim3(256), 0, stream,
                       X2, nullptr, nullptr, nullptr, 0.f, nullptr,
                       WL(3), WS(3), WP(3), BP(3), POS2,
                       SHPc, CAPc, nullptr, NN_COARSE);
    hipLaunchKernelGGL((edge_pass<32, true>), dim3(113), dim3(256), 0, stream,
                       SHPc, CAPc, e2, (float2*)Y4, NN_COARSE);
    hipLaunchKernelGGL((stats_k<32>), dim3(16), dim3(256), 0, stream,
                       Y4, 57600, STATS + 768);

    // ---- L5 (32->128) coarse, f = bn(Y4)+X2 ----
    hipLaunchKernelGGL((pass_a<32, 128, 2>), dim3(450), dim3(256), 0, stream,
                       Y4, STATS + 768, G_(3), BE(3), INV_N2, X2,
                       WL(4), WS(4), WP(4), BP(4), POS2,
                       SHPc, CAPc, nullptr, NN_COARSE);
    hipLaunchKernelGGL((edge_pass<128, true>), dim3(450), dim3(256), 0, stream,
                       SHPc, CAPc, e2, (float2*)Y5, NN_COARSE);
    hipLaunchKernelGGL((stats_k<128>), dim3(32), dim3(256), 0, stream,
                       Y5, 230400, STATS + 1024);

    // ---- pool5 + FC ----
    hipLaunchKernelGGL(pool5_k, dim3(8), dim3(256), 0, stream,
                       Y5, STATS + 1024, G_(4), BE(4), POS2, POOLED);
    hipLaunchKernelGGL(fc_k, dim3(8, 26), dim3(256), 0, stream,
                       POOLED, w_fc, (float*)d_out);
}

// Round 5
// 272.797 us; speedup vs baseline: 4.1872x; 4.1872x over previous
//
#include <hip/hip_runtime.h>

#define ENC_NEGINF 0x007FFFFFu
#define NN_FINE 100000
#define NN_COARSE 1800
#define INV_N  (1.0f / 100000.0f)
#define INV_N2 (1.0f / 1800.0f)

__device__ __forceinline__ unsigned enc_f(float f) {
    unsigned u = __float_as_uint(f);
    return (u & 0x80000000u) ? ~u : (u | 0x80000000u);
}
__device__ __forceinline__ float dec_f(unsigned k) {
    return (k & 0x80000000u) ? __uint_as_float(k & 0x7fffffffu) : __uint_as_float(~k);
}

// bijective XCD-aware swizzle (m204 variant)
__device__ __forceinline__ int xcd_swz(int bid, int nwg) {
    int q = nwg >> 3, r = nwg & 7;
    int xcd = bid & 7, idx = bid >> 3;
    return (xcd < r ? xcd * (q + 1) : r * (q + 1) + (xcd - r) * q) + idx;
}

__device__ __forceinline__ float2 bn_ss(const float* __restrict__ st,
                                        const float* __restrict__ g,
                                        const float* __restrict__ be,
                                        int r, float invn) {
    float mu  = st[r] * invn;
    float var = fmaxf(st[128 + r] * invn - mu * mu, 0.f);
    float s = g[r] * rsqrtf(var + 1e-5f);
    return make_float2(s, be[r] - mu * s);
}

// ---------------- init: zero BN stats --------------------------------------
__global__ void init_k(float* stats) {
    int t = blockIdx.x * blockDim.x + threadIdx.x;
    if (t < 1280) stats[t] = 0.f;
}

// ---------------- PassA: per (node, channel-pair) ---------------------------
// MODE 0: f=in. 1: f=bn(in), write zout=bn(in). 2: f=bn(in)+skipf.
template<int CIN, int COUT, int MODE>
__global__ void pass_a(const float* __restrict__ in,
                       const float* __restrict__ st, const float* __restrict__ g,
                       const float* __restrict__ be, float invn,
                       const float* __restrict__ skipf,
                       const float* __restrict__ wl, const float* __restrict__ wsrc,
                       const float* __restrict__ wpos, const float* __restrict__ bpos,
                       const float* __restrict__ pos,
                       float4* __restrict__ SHP, float2* __restrict__ CAP,
                       float* __restrict__ zout, int NN) {
    constexpr int P = COUT / 2;
    int idx = blockIdx.x * blockDim.x + threadIdx.x;
    int i = idx / P, p = idx % P;
    if (i >= NN) return;
    float f[CIN];
#pragma unroll
    for (int r = 0; r < CIN; ++r) {
        float v = in[i * CIN + r];
        if constexpr (MODE >= 1) {
            float2 ss = bn_ss(st, g, be, r, invn);
            v = v * ss.x + ss.y;
        }
        if constexpr (MODE == 2) v += skipf[i * CIN + r];
        f[r] = v;
    }
    int c0 = 2 * p;
    float h0 = 0.f, a0 = 0.f, h1 = 0.f, a1 = 0.f;
#pragma unroll
    for (int r = 0; r < CIN; ++r) {
        float2 wlr = *reinterpret_cast<const float2*>(&wl[r * COUT + c0]);
        float2 wsr = *reinterpret_cast<const float2*>(&wsrc[r * COUT + c0]);
        h0 += f[r] * wlr.x; h1 += f[r] * wlr.y;
        a0 += f[r] * wsr.x; a1 += f[r] * wsr.y;
    }
    float px = pos[i * 3], py = pos[i * 3 + 1], pz = pos[i * 3 + 2];
    float2 w0 = *reinterpret_cast<const float2*>(&wpos[c0]);
    float2 w1 = *reinterpret_cast<const float2*>(&wpos[COUT + c0]);
    float2 w2 = *reinterpret_cast<const float2*>(&wpos[2 * COUT + c0]);
    float pd0 = px * w0.x + py * w1.x + pz * w2.x;
    float pd1 = px * w0.y + py * w1.y + pz * w2.y;
    float2 bp = *reinterpret_cast<const float2*>(&bpos[c0]);
    SHP[i * P + p] = make_float4(a0 + pd0, a1 + pd1, h0 - pd0, h1 - pd1);
    CAP[i * P + p] = make_float2(pd0 + bp.x, pd1 + bp.y);
    if constexpr (MODE == 1) {
        float2 s0 = bn_ss(st, g, be, c0, invn);
        float2 s1 = bn_ss(st, g, be, c0 + 1, invn);
        float2 zv = make_float2(in[i * CIN + c0] * s0.x + s0.y,
                                in[i * CIN + c0 + 1] * s1.x + s1.y);
        *reinterpret_cast<float2*>(&zout[i * CIN + c0]) = zv;
    }
}

// ---------------- Edge pass: 1 float4 gather per edge, no atomics -----------
template<int C, bool COARSE>
__global__ __launch_bounds__(256, 4)
void edge_pass(const float4* __restrict__ SHP, const float2* __restrict__ CAP,
               const int* __restrict__ esrc, float2* __restrict__ y2, int NN) {
    constexpr int P = C / 2;
    constexpr int NPB = 256 / P;
    constexpr int DEG_ = COARSE ? 8 : 16;
    __shared__ int se[NPB * DEG_];
    int bid = COARSE ? (int)blockIdx.x : xcd_swz(blockIdx.x, gridDim.x);
    int tid = threadIdx.x;
    int node0 = bid * NPB;
    if constexpr (!COARSE) {
        for (int t = tid; t < NPB * DEG_; t += 256)
            se[t] = esrc[node0 * 16 + t];          // in-bounds: dst half follows src
    } else {
        for (int t = tid; t < NPB * DEG_; t += 256) {
            int n = t / DEG_, e = t % DEG_;
            int i2 = node0 + n;
            if (i2 < NN) {
                int b = i2 / 225, j = i2 % 225;
                se[t] = esrc[b * 1800 + e * 225 + j];
            }
        }
    }
    __syncthreads();
    int n = tid / P, p = tid % P;
    int i = node0 + n;
    if (i >= NN) return;

    float4 q[DEG_ + 1];
#pragma unroll
    for (int e = 0; e < DEG_; ++e)
        q[e] = SHP[(size_t)se[n * DEG_ + e] * P + p];
    q[DEG_] = SHP[(size_t)i * P + p];

    float smin0 = q[0].x, smin1 = q[0].y;
#pragma unroll
    for (int e = 1; e <= DEG_; ++e) {
        smin0 = fminf(smin0, q[e].x);
        smin1 = fminf(smin1, q[e].y);
    }
    float den0 = 0.f, acc0 = 0.f, den1 = 0.f, acc1 = 0.f;
#pragma unroll
    for (int e = 0; e <= DEG_; ++e) {
        float ex0 = __expf(smin0 - q[e].x);
        float ex1 = __expf(smin1 - q[e].y);
        den0 += ex0; acc0 += ex0 * q[e].z;
        den1 += ex1; acc1 += ex1 * q[e].w;
    }
    float2 Ci = CAP[(size_t)i * P + p];
    float o0 = (acc0 + Ci.x * den0) / (den0 + 1e-16f);
    float o1 = (acc1 + Ci.y * den1) / (den1 + 1e-16f);
    float y0 = o0 > 0.f ? o0 : (__expf(o0) - 1.f);
    float y1 = o1 > 0.f ? o1 : (__expf(o1) - 1.f);
    y2[(size_t)i * P + p] = make_float2(y0, y1);
}

// ---------------- BN stats over y -------------------------------------------
template<int C>
__global__ void stats_k(const float* __restrict__ y, int total,
                        float* __restrict__ stats) {
    __shared__ float ls[C], lq[C];
    int tid = threadIdx.x;
    if (tid < C) { ls[tid] = 0.f; lq[tid] = 0.f; }
    __syncthreads();
    float s1 = 0.f, s2 = 0.f;
    int stride = gridDim.x * 256;
    int c = tid % C;   // stride and block offset are multiples of C
    for (int k = blockIdx.x * 256 + tid; k < total; k += stride) {
        float v = y[k];
        s1 += v; s2 += v * v;
    }
    if constexpr (C <= 32) {
#pragma unroll
        for (int m = C; m < 64; m <<= 1) {
            s1 += __shfl_xor(s1, m);
            s2 += __shfl_xor(s2, m);
        }
        if ((tid & 63) < C) { atomicAdd(&ls[c], s1); atomicAdd(&lq[c], s2); }
    } else {
        atomicAdd(&ls[c], s1); atomicAdd(&lq[c], s2);
    }
    __syncthreads();
    if (tid < C) {
        atomicAdd(&stats[tid], ls[tid]);
        atomicAdd(&stats[128 + tid], lq[tid]);
    }
}

// ---------------- pool3 stage 1: 32 blocks/sample, private LDS, partials ----
// partials: PK[bid][7200] uint, PC[bid][225], PP[bid][675]
__global__ __launch_bounds__(256)
void pool3a(const float* __restrict__ y3, const float* __restrict__ st,
            const float* __restrict__ g, const float* __restrict__ be,
            const float* __restrict__ pos,
            unsigned* __restrict__ PK, float* __restrict__ PC,
            float* __restrict__ PP) {
    __shared__ unsigned lkey[7200];
    __shared__ float lcnt[225];
    __shared__ float lpac[675];
    int tid = threadIdx.x;
    for (int t = tid; t < 7200; t += 256) lkey[t] = ENC_NEGINF;
    if (tid < 225) lcnt[tid] = 0.f;
    for (int t = tid; t < 675; t += 256) lpac[t] = 0.f;
    __syncthreads();
    int bid = blockIdx.x;
    int s = bid >> 5, sb = bid & 31;
    int beg = s * 12500 + sb * 391;
    int end = min(s * 12500 + 12500, beg + 391);
    int c = tid & 31, nl = tid >> 5;
    float2 ss = bn_ss(st, g, be, c, INV_N);
    for (int i = beg + nl; i < end; i += 8) {
        float z = y3[(size_t)i * 32 + c] * ss.x + ss.y;
        float px = pos[i * 3], py = pos[i * 3 + 1];
        int cx = min(max((int)floorf(px / 16.f), 0), 14);
        int cy = min(max((int)floorf(py / 12.f), 0), 14);
        int cl = cy * 15 + cx;
        atomicMax(&lkey[cl * 32 + c], enc_f(z));
        if (c == 0) {
            atomicAdd(&lcnt[cl], 1.f);
            atomicAdd(&lpac[cl * 3 + 0], px);
            atomicAdd(&lpac[cl * 3 + 1], py);
            atomicAdd(&lpac[cl * 3 + 2], pos[i * 3 + 2]);
        }
    }
    __syncthreads();
    for (int t = tid; t < 7200; t += 256) PK[(size_t)bid * 7200 + t] = lkey[t];
    if (tid < 225) PC[bid * 225 + tid] = lcnt[tid];
    for (int t = tid; t < 675; t += 256) PP[bid * 675 + t] = lpac[t];
}

// ---------------- pool3 stage 2: reduce 32 partials -> X2, POS2 -------------
__global__ void pool3b(const unsigned* __restrict__ PK, const float* __restrict__ PC,
                       const float* __restrict__ PP,
                       float* __restrict__ X2, float* __restrict__ POS2) {
    int idx = blockIdx.x * blockDim.x + threadIdx.x;
    if (idx < 57600) {
        int s = idx / 7200, t = idx % 7200;
        unsigned m = ENC_NEGINF;
#pragma unroll 8
        for (int sb = 0; sb < 32; ++sb)
            m = max(m, PK[(size_t)(s * 32 + sb) * 7200 + t]);
        X2[idx] = (m == ENC_NEGINF) ? 0.f : dec_f(m);
    } else if (idx < 63000) {
        int j = idx - 57600;
        int s = j / 675, r = j % 675;
        int cl = r / 3;
        float sp = 0.f, sc = 0.f;
#pragma unroll 8
        for (int sb = 0; sb < 32; ++sb) {
            sp += PP[(s * 32 + sb) * 675 + r];
            sc += PC[(s * 32 + sb) * 225 + cl];
        }
        POS2[j] = sp / fmaxf(sc, 1.f);
    }
}

// ---------------- pool5: one block per sample, 1024 thr, LDS max ------------
__global__ __launch_bounds__(1024)
void pool5_k(const float* __restrict__ y5, const float* __restrict__ st,
             const float* __restrict__ g, const float* __restrict__ be,
             const float* __restrict__ POS2, float* __restrict__ POOLED) {
    __shared__ unsigned lkey[2048];   // 16 cells x 128 ch
    int tid = threadIdx.x;
    for (int t = tid; t < 2048; t += 1024) lkey[t] = ENC_NEGINF;
    __syncthreads();
    int s = blockIdx.x;
    int c = tid & 127, nl = tid >> 7;
    float2 ss = bn_ss(st, g, be, c, INV_N2);
    for (int j = nl; j < 225; j += 8) {
        int i = s * 225 + j;
        float z = y5[(size_t)i * 128 + c] * ss.x + ss.y;
        float px = POS2[i * 3], py = POS2[i * 3 + 1];
        int cx = min(max((int)floorf(px / 60.f), 0), 3);
        int cy = min(max((int)floorf(py / 45.f), 0), 3);
        int cell = (cy * 4 + cx) * 128 + c;
        atomicMax(&lkey[cell], enc_f(z));
    }
    __syncthreads();
    for (int t = tid; t < 2048; t += 1024) {
        unsigned k = lkey[t];
        POOLED[s * 2048 + t] = (k == ENC_NEGINF) ? 0.f : dec_f(k);
    }
}

// ---------------- FC --------------------------------------------------------
__global__ void fc_k(const float* __restrict__ pooled, const float* __restrict__ wfc,
                     float* __restrict__ out) {
    __shared__ float row[2048];
    int b = blockIdx.x;
    for (int k = threadIdx.x; k < 2048; k += 256)
        row[k] = pooled[b * 2048 + k];
    __syncthreads();
    int wave = threadIdx.x >> 6, lane = threadIdx.x & 63;
    int o = blockIdx.y * 4 + wave;
    if (o < 101) {
        float a = 0.f;
        for (int k = lane; k < 2048; k += 64)
            a += row[k] * wfc[k * 101 + o];
#pragma unroll
        for (int m = 32; m; m >>= 1) a += __shfl_xor(a, m);
        if (lane == 0) out[b * 101 + o] = a;
    }
}

extern "C" void kernel_launch(void* const* d_in, const int* in_sizes, int n_in,
                              void* d_out, int out_size, void* d_ws, size_t ws_size,
                              hipStream_t stream) {
    const float* x     = (const float*)d_in[0];
    const float* pos   = (const float*)d_in[1];
    const int*   e1    = (const int*)d_in[3];
    const int*   e2    = (const int*)d_in[4];
    const float* w_fc  = (const float*)d_in[40];
    auto WL = [&](int l) { return (const float*)d_in[5 + l * 7 + 0]; };
    auto WS = [&](int l) { return (const float*)d_in[5 + l * 7 + 1]; };
    auto WP = [&](int l) { return (const float*)d_in[5 + l * 7 + 3]; };
    auto BP = [&](int l) { return (const float*)d_in[5 + l * 7 + 4]; };
    auto G_ = [&](int l) { return (const float*)d_in[5 + l * 7 + 5]; };
    auto BE = [&](int l) { return (const float*)d_in[5 + l * 7 + 6]; };

    float* W = (float*)d_ws;
    size_t o = 0;
    float4* SHPf = (float4*)W;        o += 6400000;  // N*16 float4 (L1..L3)
    float2* CAPf = (float2*)(W + o);  o += 3200000;
    float*  Y1   = W + o;             o += 800000;
    float*  Y2   = W + o;             o += 800000;
    float*  Z1   = W + o;             o += 800000;
    float*  Y3   = W + o;             o += 3200000;
    float*  STATS = W + o;            o += 5 * 256;
    float*  X2   = W + o;             o += 57600;
    float*  POS2 = W + o;             o += 5400;
    float4* SHPc = (float4*)(W + o);  o += 460800;   // 1800*64 float4
    float2* CAPc = (float2*)(W + o);  o += 230400;
    float*  Y4   = W + o;             o += 57600;
    float*  Y5   = W + o;             o += 230400;
    float*  POOLED = W + o;           o += 16384;
    // pool3 partials alias the (dead after L3 edge) SHPf region:
    unsigned* PK = (unsigned*)W;                  // 256*7200 u32 = 1.84M
    float*    PC = W + 2000000;                   // 256*225
    float*    PP = W + 2100000;                   // 256*675

    hipLaunchKernelGGL(init_k, dim3(5), dim3(256), 0, stream, STATS);

    // ---- L1 (1->8) fine ----
    hipLaunchKernelGGL((pass_a<1, 8, 0>), dim3(1563), dim3(256), 0, stream,
                       x, nullptr, nullptr, nullptr, 0.f, nullptr,
                       WL(0), WS(0), WP(0), BP(0), pos,
                       SHPf, CAPf, nullptr, NN_FINE);
    hipLaunchKernelGGL((edge_pass<8, false>), dim3(1563), dim3(256), 0, stream,
                       SHPf, CAPf, e1, (float2*)Y1, NN_FINE);
    hipLaunchKernelGGL((stats_k<8>), dim3(64), dim3(256), 0, stream,
                       Y1, 800000, STATS + 0);

    // ---- L2 (8->8) fine, writes Z1=bn(Y1) ----
    hipLaunchKernelGGL((pass_a<8, 8, 1>), dim3(1563), dim3(256), 0, stream,
                       Y1, STATS + 0, G_(0), BE(0), INV_N, nullptr,
                       WL(1), WS(1), WP(1), BP(1), pos,
                       SHPf, CAPf, Z1, NN_FINE);
    hipLaunchKernelGGL((edge_pass<8, false>), dim3(1563), dim3(256), 0, stream,
                       SHPf, CAPf, e1, (float2*)Y2, NN_FINE);
    hipLaunchKernelGGL((stats_k<8>), dim3(64), dim3(256), 0, stream,
                       Y2, 800000, STATS + 256);

    // ---- L3 (8->32) fine, f = bn(Y2)+Z1 ----
    hipLaunchKernelGGL((pass_a<8, 32, 2>), dim3(6250), dim3(256), 0, stream,
                       Y2, STATS + 256, G_(1), BE(1), INV_N, Z1,
                       WL(2), WS(2), WP(2), BP(2), pos,
                       SHPf, CAPf, nullptr, NN_FINE);
    hipLaunchKernelGGL((edge_pass<32, false>), dim3(6250), dim3(256), 0, stream,
                       SHPf, CAPf, e1, (float2*)Y3, NN_FINE);
    hipLaunchKernelGGL((stats_k<32>), dim3(64), dim3(256), 0, stream,
                       Y3, 3200000, STATS + 512);

    // ---- pool3: two-stage (SHPf region is dead now; partials alias it) ----
    hipLaunchKernelGGL(pool3a, dim3(256), dim3(256), 0, stream,
                       Y3, STATS + 512, G_(2), BE(2), pos, PK, PC, PP);
    hipLaunchKernelGGL(pool3b, dim3(247), dim3(256), 0, stream,
                       PK, PC, PP, X2, POS2);

    // ---- L4 (32->32) coarse ----
    hipLaunchKernelGGL((pass_a<32, 32, 0>), dim3(113), dim3(256), 0, stream,
                       X2, nullptr, nullptr, nullptr, 0.f, nullptr,
                       WL(3), WS(3), WP(3), BP(3), POS2,
                       SHPc, CAPc, nullptr, NN_COARSE);
    hipLaunchKernelGGL((edge_pass<32, true>), dim3(113), dim3(256), 0, stream,
                       SHPc, CAPc, e2, (float2*)Y4, NN_COARSE);
    hipLaunchKernelGGL((stats_k<32>), dim3(16), dim3(256), 0, stream,
                       Y4, 57600, STATS + 768);

    // ---- L5 (32->128) coarse, f = bn(Y4)+X2 ----
    hipLaunchKernelGGL((pass_a<32, 128, 2>), dim3(450), dim3(256), 0, stream,
                       Y4, STATS + 768, G_(3), BE(3), INV_N2, X2,
                       WL(4), WS(4), WP(4), BP(4), POS2,
                       SHPc, CAPc, nullptr, NN_COARSE);
    hipLaunchKernelGGL((edge_pass<128, true>), dim3(450), dim3(256), 0, stream,
                       SHPc, CAPc, e2, (float2*)Y5, NN_COARSE);
    hipLaunchKernelGGL((stats_k<128>), dim3(32), dim3(256), 0, stream,
                       Y5, 230400, STATS + 1024);

    // ---- pool5 + FC ----
    hipLaunchKernelGGL(pool5_k, dim3(8), dim3(1024), 0, stream,
                       Y5, STATS + 1024, G_(4), BE(4), POS2, POOLED);
    hipLaunchKernelGGL(fc_k, dim3(8, 26), dim3(256), 0, stream,
                       POOLED, w_fc, (float*)d_out);
}